// Round 11
// baseline (233.287 us; speedup 1.0000x reference)
//
#include <hip/hip_runtime.h>
#include <hip/hip_bf16.h>

#define N_NODES 100000
#define N_TYPE  50000
#define NB1     192        // partition blocks
#define EPB1    8334       // edges per partition block (192*8334 >= 1.6M)
#define NBUCK   782        // ceil(100000/128) row buckets
#define BROWS   128        // rows per bucket
#define CAP     2304       // per-bucket capacity (mean 2048, sd ~45; +5.7 sigma)

typedef short bf16x8 __attribute__((ext_vector_type(8)));
typedef float f32x4  __attribute__((ext_vector_type(4)));
typedef unsigned short u16x4 __attribute__((ext_vector_type(4)));

__device__ inline unsigned short f2bf(float f) {
  union { float f; unsigned u; } x; x.f = f;
  unsigned r = (x.u + 0x7fff + ((x.u >> 16) & 1)) >> 16;  // RNE
  return (unsigned short)r;
}
__device__ inline float bf2f(unsigned short h) {
  union { unsigned u; float f; } x; x.u = ((unsigned)h) << 16;
  return x.f;
}

// ---------------- prep: bf16 transposed weights + combined bias + padded head weights --------
__global__ __launch_bounds__(256) void prep_small_kernel(
    const float* __restrict__ fc0_w, const float* __restrict__ fc1_w,
    const float* __restrict__ fc0_b, const float* __restrict__ fc1_b,
    const float* __restrict__ W1, const float* __restrict__ W2,
    const float* __restrict__ pred_w,
    unsigned short* __restrict__ M0T, unsigned short* __restrict__ M1T,
    unsigned short* __restrict__ W2T, unsigned short* __restrict__ pwT,
    float* __restrict__ cb) {
  int idx = blockIdx.x * 256 + threadIdx.x;
  if (idx < 16384) {                       // M0T[n=128][k=128]
    int i = idx >> 7, j = idx & 127;
    float s = 0.f;
    #pragma unroll 4
    for (int o = 0; o < 128; ++o) s = fmaf(fc0_w[o * 128 + i], W1[o * 128 + j], s);
    M0T[j * 128 + i] = f2bf(s);
  } else if (idx < 49152) {                // M1T[n=128][k=256]
    int r = idx - 16384;
    int i = r >> 7, j = r & 127;
    float s = 0.f;
    #pragma unroll 4
    for (int o = 0; o < 128; ++o) s = fmaf(fc1_w[o * 256 + i], W1[o * 128 + j], s);
    M1T[j * 256 + i] = f2bf(s);
  } else if (idx < 57344) {                // W2T[n=64][k=128]
    int r = idx - 49152;
    int k = r >> 6, n = r & 63;
    W2T[n * 128 + k] = f2bf(W2[k * 64 + n]);
  } else if (idx < 57600) {                // cb[256]
    int r = idx - 57344;
    int t = r >> 7, j = r & 127;
    const float* bb = t ? fc1_b : fc0_b;
    float s = 0.f;
    for (int o = 0; o < 128; ++o) s = fmaf(bb[o], W1[o * 128 + j], s);
    cb[r] = s;
  } else if (idx < 58624) {                // pwT[16][64], rows 8..15 zero-padded
    int r = idx - 57600;
    int n = r >> 6, k = r & 63;
    pwT[r] = (n < 8) ? f2bf(pred_w[n * 64 + k]) : (unsigned short)0;
  }
}

// ---------------- bf16 MFMA GEMM (fp32 A input, feature projections) -------------------------
template <int NC, int KTOT>
__global__ __launch_bounds__(256) void mfma_gemm_kernel(
    const float* __restrict__ A, const unsigned short* __restrict__ BT,
    const float* __restrict__ bc, unsigned short* __restrict__ Cout, int M) {
  constexpr int NREP = NC / 32;
  __shared__ unsigned short As[64 * 128];
  __shared__ unsigned short Bs[NC * 128];

  const int tid = threadIdx.x;
  const int row0 = blockIdx.x * 64;
  const int wave = tid >> 6, lane = tid & 63;
  const int wr = wave >> 1, wc = wave & 1;
  const int lm = lane & 15;
  const int lk16 = (lane >> 4) * 16;

  f32x4 acc[2][NREP];
  #pragma unroll
  for (int i = 0; i < 2; ++i)
    #pragma unroll
    for (int j = 0; j < NREP; ++j) acc[i][j] = (f32x4){0.f, 0.f, 0.f, 0.f};

  for (int kc = 0; kc < KTOT; kc += 128) {
    if (kc) __syncthreads();
    {
      const int r = tid >> 2;
      const int cg = tid & 3;
      int gr = row0 + r; if (gr > M - 1) gr = M - 1;
      const float* arow = A + (size_t)gr * KTOT + kc;
      char* asrow = (char*)As + r * 256;
      const int swz = (r & 7) << 4;
      #pragma unroll
      for (int i = 0; i < 8; ++i) {
        const int c = i * 4 + cg;
        float4 v = *(const float4*)(arow + c * 4);
        u16x4 q = {f2bf(v.x), f2bf(v.y), f2bf(v.z), f2bf(v.w)};
        *(u16x4*)(asrow + ((c * 8) ^ swz)) = q;
      }
    }
    {
      constexpr int CHUNKS = NC * 16;
      #pragma unroll
      for (int i = 0; i < CHUNKS / 256; ++i) {
        const int id = i * 256 + tid;
        const int n = id >> 4, k16 = id & 15;
        const uint4 w = *(const uint4*)((const char*)BT + ((size_t)n * KTOT + kc) * 2 + k16 * 16);
        *(uint4*)((char*)Bs + ((n * 256 + k16 * 16) ^ ((n & 7) << 4))) = w;
      }
    }
    __syncthreads();
    #pragma unroll
    for (int ks = 0; ks < 4; ++ks) {
      bf16x8 a[2];
      #pragma unroll
      for (int m = 0; m < 2; ++m) {
        const int r = wr * 32 + m * 16 + lm;
        a[m] = *(bf16x8*)((char*)As + ((r * 256 + ks * 64 + lk16) ^ ((r & 7) << 4)));
      }
      #pragma unroll
      for (int j = 0; j < NREP; ++j) {
        const int n = wc * (NC / 2) + j * 16 + lm;
        const bf16x8 b = *(bf16x8*)((char*)Bs + ((n * 256 + ks * 64 + lk16) ^ ((n & 7) << 4)));
        acc[0][j] = __builtin_amdgcn_mfma_f32_16x16x32_bf16(a[0], b, acc[0][j], 0, 0, 0);
        acc[1][j] = __builtin_amdgcn_mfma_f32_16x16x32_bf16(a[1], b, acc[1][j], 0, 0, 0);
      }
    }
  }
  #pragma unroll
  for (int m = 0; m < 2; ++m) {
    const int gr0 = row0 + wr * 32 + m * 16 + (lane >> 4) * 4;
    #pragma unroll
    for (int j = 0; j < NREP; ++j) {
      const int col = wc * (NC / 2) + j * 16 + lm;
      const float cbv = bc[col];
      #pragma unroll
      for (int i = 0; i < 4; ++i) {
        const int gr = gr0 + i;
        if (gr < M) Cout[(size_t)gr * NC + col] = f2bf(acc[m][j][i] + cbv);
      }
    }
  }
}

// ---------------- bf16-A GEMM: h2[M][64] = g1_bf16[M][128] @ W2T^T ---------------------------
__global__ __launch_bounds__(256) void gemmA64_kernel(
    const unsigned short* __restrict__ A, const unsigned short* __restrict__ BT,
    unsigned short* __restrict__ Cout, int M) {
  __shared__ unsigned short As[64 * 128];   // 16 KB
  __shared__ unsigned short Bs[64 * 128];   // 16 KB
  const int tid = threadIdx.x;
  const int row0 = blockIdx.x * 64;
  const int wave = tid >> 6, lane = tid & 63;
  const int wr = wave >> 1, wc = wave & 1;
  const int lm = lane & 15, lk16 = (lane >> 4) * 16;
  {
    const int r = tid >> 2, cg = tid & 3;
    int gr = row0 + r; if (gr > M - 1) gr = M - 1;
    const uint4* arow = (const uint4*)(A + (size_t)gr * 128);
    const int swz = (r & 7) << 4;
    #pragma unroll
    for (int i = 0; i < 4; ++i) {
      const int c16 = i * 4 + cg;
      const uint4 w = arow[c16];
      *(uint4*)((char*)As + ((r * 256 + c16 * 16) ^ swz)) = w;
    }
  }
  #pragma unroll
  for (int i = 0; i < 4; ++i) {
    const int id = i * 256 + tid;
    const int n = id >> 4, k16 = id & 15;
    const uint4 w = *(const uint4*)((const char*)BT + n * 256 + k16 * 16);
    *(uint4*)((char*)Bs + ((n * 256 + k16 * 16) ^ ((n & 7) << 4))) = w;
  }
  __syncthreads();
  f32x4 acc[2][2];
  #pragma unroll
  for (int i = 0; i < 2; ++i)
    #pragma unroll
    for (int j = 0; j < 2; ++j) acc[i][j] = (f32x4){0.f, 0.f, 0.f, 0.f};
  #pragma unroll
  for (int ks = 0; ks < 4; ++ks) {
    bf16x8 a[2];
    #pragma unroll
    for (int m = 0; m < 2; ++m) {
      const int r = wr * 32 + m * 16 + lm;
      a[m] = *(bf16x8*)((char*)As + ((r * 256 + ks * 64 + lk16) ^ ((r & 7) << 4)));
    }
    #pragma unroll
    for (int j = 0; j < 2; ++j) {
      const int n = wc * 32 + j * 16 + lm;
      const bf16x8 b = *(bf16x8*)((char*)Bs + ((n * 256 + ks * 64 + lk16) ^ ((n & 7) << 4)));
      acc[0][j] = __builtin_amdgcn_mfma_f32_16x16x32_bf16(a[0], b, acc[0][j], 0, 0, 0);
      acc[1][j] = __builtin_amdgcn_mfma_f32_16x16x32_bf16(a[1], b, acc[1][j], 0, 0, 0);
    }
  }
  #pragma unroll
  for (int m = 0; m < 2; ++m) {
    const int gr0 = row0 + wr * 32 + m * 16 + (lane >> 4) * 4;
    #pragma unroll
    for (int j = 0; j < 2; ++j) {
      const int col = wc * 32 + j * 16 + lm;
      #pragma unroll
      for (int i = 0; i < 4; ++i) {
        const int gr = gr0 + i;
        if (gr < M) Cout[(size_t)gr * 64 + col] = f2bf(acc[m][j][i]);
      }
    }
  }
}

// ---- hist1: per-(block,bucket) histogram; NO global atomics ---------------------------------
__global__ __launch_bounds__(512) void hist1_kernel(
    const int* __restrict__ erow, int* __restrict__ gh, int nE) {
  __shared__ int lh[NBUCK];
  const int t = threadIdx.x;
  const int e0 = blockIdx.x * EPB1;
  const int e1 = min(e0 + EPB1, nE);
  for (int i = t; i < NBUCK; i += 512) lh[i] = 0;
  __syncthreads();
  for (int i = e0 + t; i < e1; i += 512) atomicAdd(&lh[erow[i] / BROWS], 1);
  __syncthreads();
  for (int i = t; i < NBUCK; i += 512) gh[i * NB1 + blockIdx.x] = lh[i];
}

// ---- scan: per-bucket serial scan over blocks -> gbase[blk][bucket], bcnt[bucket] -----------
__global__ __launch_bounds__(1024) void scan_kernel(
    const int* __restrict__ gh, int* __restrict__ gbase, int* __restrict__ bcnt) {
  const int t = blockIdx.x * 1024 + threadIdx.x;
  if (t >= NBUCK) return;
  int run = t * CAP;
  for (int blk = 0; blk < NB1; ++blk) {
    gbase[blk * NBUCK + t] = run;
    run += gh[t * NB1 + blk];
  }
  bcnt[t] = run - t * CAP;
}

// ---- scatter1: write records to reserved runs (LDS atomics only) ----------------------------
__global__ __launch_bounds__(512) void scatter1_kernel(
    const int* __restrict__ erow, const int* __restrict__ ecol,
    const float* __restrict__ ew, const int* __restrict__ gbase,
    uint2* __restrict__ tmp, int nE) {
  __shared__ int lh[NBUCK];
  __shared__ int lbase[NBUCK];
  const int t = threadIdx.x;
  const int e0 = blockIdx.x * EPB1;
  const int e1 = min(e0 + EPB1, nE);
  for (int i = t; i < NBUCK; i += 512) {
    lh[i] = 0;
    lbase[i] = gbase[blockIdx.x * NBUCK + i];
  }
  __syncthreads();
  for (int i = e0 + t; i < e1; i += 512) {
    const int r = erow[i];
    const int b = r / BROWS;
    const int pos = lbase[b] + atomicAdd(&lh[b], 1);
    const unsigned short bw = f2bf(ew[i]);             // w in [0,1): sign 0, fits 15 bits
    const unsigned rec = ((unsigned)ecol[i] << 15) | (unsigned)bw;
    tmp[pos] = make_uint2(rec, (unsigned)r);
  }
}

// ---- part2: per-bucket (128 rows) counting sort into row order; emits row_se ----------------
__global__ __launch_bounds__(256) void part2_kernel(
    const int* __restrict__ bcnt, const uint2* __restrict__ tmp,
    unsigned* __restrict__ spack, int2* __restrict__ row_se, int N) {
  __shared__ int hist[BROWS];
  __shared__ int scn[BROWS];
  __shared__ int cur[BROWS];
  const int b = blockIdx.x;
  const int r0 = b * BROWS;
  const int t = threadIdx.x;
  const int base = b * CAP;
  const int cnt = bcnt[b];
  const uint2* rec = tmp + base;
  if (t < BROWS) hist[t] = 0;
  __syncthreads();
  for (int i = t; i < cnt; i += 256)
    atomicAdd(&hist[(int)rec[i].y - r0], 1);
  __syncthreads();
  int v = 0;
  if (t < BROWS) { v = hist[t]; scn[t] = v; }
  __syncthreads();
  #pragma unroll
  for (int off = 1; off < BROWS; off <<= 1) {
    int y = (t >= off && t < BROWS) ? scn[t - off] : 0;
    __syncthreads();
    if (t < BROWS) scn[t] += y;
    __syncthreads();
  }
  if (t < BROWS) {
    const int excl = base + scn[t] - v;
    const int r = r0 + t;
    if (r < N) row_se[r] = make_int2(excl, excl + v);
    cur[t] = excl;
  }
  __syncthreads();
  for (int i = t; i < cnt; i += 256) {
    const uint2 rc = rec[i];
    const int pos = atomicAdd(&cur[(int)rc.y - r0], 1);
    spack[pos] = rc.x;
  }
}

// ---- spmm1: g1 = bf16(relu(adj @ h + b1)); 32 lanes/row, u16x4 (8B) gathers, unroll 4 -------
__global__ __launch_bounds__(256) void spmm1_kernel(
    const unsigned short* __restrict__ h, const int2* __restrict__ row_se,
    const unsigned* __restrict__ spack, const float* __restrict__ b1,
    unsigned short* __restrict__ g1, int M) {
  const int r = (blockIdx.x * 256 + threadIdx.x) >> 5;
  const int lane = threadIdx.x & 31;
  if (r >= M) return;
  const int2 se = row_se[r];
  f32x4 acc = (f32x4){0.f, 0.f, 0.f, 0.f};
  int j = se.x;
  for (; j + 3 < se.y; j += 4) {
    const unsigned rc0 = spack[j], rc1 = spack[j + 1];
    const unsigned rc2 = spack[j + 2], rc3 = spack[j + 3];
    const u16x4 v0 = *(const u16x4*)(h + (size_t)(rc0 >> 15) * 128 + lane * 4);
    const u16x4 v1 = *(const u16x4*)(h + (size_t)(rc1 >> 15) * 128 + lane * 4);
    const u16x4 v2 = *(const u16x4*)(h + (size_t)(rc2 >> 15) * 128 + lane * 4);
    const u16x4 v3 = *(const u16x4*)(h + (size_t)(rc3 >> 15) * 128 + lane * 4);
    const float w0 = bf2f((unsigned short)(rc0 & 0x7fff));
    const float w1 = bf2f((unsigned short)(rc1 & 0x7fff));
    const float w2 = bf2f((unsigned short)(rc2 & 0x7fff));
    const float w3 = bf2f((unsigned short)(rc3 & 0x7fff));
    #pragma unroll
    for (int k = 0; k < 4; ++k) {
      acc[k] = fmaf(bf2f(v0[k]), w0, acc[k]);
      acc[k] = fmaf(bf2f(v1[k]), w1, acc[k]);
      acc[k] = fmaf(bf2f(v2[k]), w2, acc[k]);
      acc[k] = fmaf(bf2f(v3[k]), w3, acc[k]);
    }
  }
  for (; j < se.y; ++j) {
    const unsigned rc0 = spack[j];
    const u16x4 v0 = *(const u16x4*)(h + (size_t)(rc0 >> 15) * 128 + lane * 4);
    const float w0 = bf2f((unsigned short)(rc0 & 0x7fff));
    #pragma unroll
    for (int k = 0; k < 4; ++k) acc[k] = fmaf(bf2f(v0[k]), w0, acc[k]);
  }
  const float4 bb = *(const float4*)(b1 + lane * 4);
  u16x4 o;
  o[0] = f2bf(fmaxf(acc[0] + bb.x, 0.f));
  o[1] = f2bf(fmaxf(acc[1] + bb.y, 0.f));
  o[2] = f2bf(fmaxf(acc[2] + bb.z, 0.f));
  o[3] = f2bf(fmaxf(acc[3] + bb.w, 0.f));
  *(u16x4*)(g1 + (size_t)r * 128 + lane * 4) = o;
}

// ---- spmm2: g2 = bf16(relu(adj @ h2 + b2)); 32 lanes/row, ushort2 (4B) gathers --------------
__global__ __launch_bounds__(256) void spmm2_kernel(
    const unsigned short* __restrict__ h2, const int2* __restrict__ row_se,
    const unsigned* __restrict__ spack, const float* __restrict__ b2,
    unsigned short* __restrict__ g2, int M) {
  const int r = (blockIdx.x * 256 + threadIdx.x) >> 5;
  const int lane = threadIdx.x & 31;
  if (r >= M) return;
  const int2 se = row_se[r];
  float2 acc = make_float2(0.f, 0.f);
  int j = se.x;
  for (; j + 3 < se.y; j += 4) {
    const unsigned rc0 = spack[j], rc1 = spack[j + 1];
    const unsigned rc2 = spack[j + 2], rc3 = spack[j + 3];
    const ushort2 v0 = *(const ushort2*)(h2 + (size_t)(rc0 >> 15) * 64 + lane * 2);
    const ushort2 v1 = *(const ushort2*)(h2 + (size_t)(rc1 >> 15) * 64 + lane * 2);
    const ushort2 v2 = *(const ushort2*)(h2 + (size_t)(rc2 >> 15) * 64 + lane * 2);
    const ushort2 v3 = *(const ushort2*)(h2 + (size_t)(rc3 >> 15) * 64 + lane * 2);
    const float w0 = bf2f((unsigned short)(rc0 & 0x7fff));
    const float w1 = bf2f((unsigned short)(rc1 & 0x7fff));
    const float w2 = bf2f((unsigned short)(rc2 & 0x7fff));
    const float w3 = bf2f((unsigned short)(rc3 & 0x7fff));
    acc.x = fmaf(bf2f(v0.x), w0, acc.x);
    acc.y = fmaf(bf2f(v0.y), w0, acc.y);
    acc.x = fmaf(bf2f(v1.x), w1, acc.x);
    acc.y = fmaf(bf2f(v1.y), w1, acc.y);
    acc.x = fmaf(bf2f(v2.x), w2, acc.x);
    acc.y = fmaf(bf2f(v2.y), w2, acc.y);
    acc.x = fmaf(bf2f(v3.x), w3, acc.x);
    acc.y = fmaf(bf2f(v3.y), w3, acc.y);
  }
  for (; j < se.y; ++j) {
    const unsigned rc0 = spack[j];
    const ushort2 v0 = *(const ushort2*)(h2 + (size_t)(rc0 >> 15) * 64 + lane * 2);
    const float w0 = bf2f((unsigned short)(rc0 & 0x7fff));
    acc.x = fmaf(bf2f(v0.x), w0, acc.x);
    acc.y = fmaf(bf2f(v0.y), w0, acc.y);
  }
  ushort2 o;
  o.x = f2bf(fmaxf(acc.x + b2[lane * 2], 0.f));
  o.y = f2bf(fmaxf(acc.y + b2[lane * 2 + 1], 0.f));
  *(ushort2*)(g2 + (size_t)r * 64 + lane * 2) = o;
}

// ---- head: out[M][8] = g2[M][64] @ pwT^T + pred_b (MFMA, 64 rows/block) ---------------------
__global__ __launch_bounds__(256) void head_kernel(
    const unsigned short* __restrict__ g2, const unsigned short* __restrict__ pwT,
    const float* __restrict__ pred_b, float* __restrict__ out, int M) {
  __shared__ unsigned short As[64 * 64];    // 8 KB
  __shared__ unsigned short Bs[16 * 64];    // 2 KB
  const int tid = threadIdx.x;
  const int wave = tid >> 6, lane = tid & 63;
  const int row0 = blockIdx.x * 64;
  if (tid < 128) {
    const int n = tid >> 3, k16 = tid & 7;
    const uint4 w = *(const uint4*)((const char*)pwT + n * 128 + k16 * 16);
    *(uint4*)((char*)Bs + ((n * 128 + k16 * 16) ^ ((n & 7) << 4))) = w;
  }
  #pragma unroll
  for (int i = 0; i < 2; ++i) {
    const int id = i * 256 + tid;
    const int rr = id >> 3, k16 = id & 7;
    int gr = row0 + rr; if (gr > M - 1) gr = M - 1;
    const uint4 w = *(const uint4*)(g2 + (size_t)gr * 64 + k16 * 8);
    *(uint4*)((char*)As + ((rr * 128 + k16 * 16) ^ ((rr & 7) << 4))) = w;
  }
  __syncthreads();
  const int lm = lane & 15, lk16 = (lane >> 4) * 16;
  f32x4 acc4 = (f32x4){0.f, 0.f, 0.f, 0.f};
  #pragma unroll
  for (int ks = 0; ks < 2; ++ks) {
    const int rrow = wave * 16 + lm;
    const bf16x8 a = *(bf16x8*)((char*)As + ((rrow * 128 + ks * 64 + lk16) ^ ((rrow & 7) << 4)));
    const bf16x8 b = *(bf16x8*)((char*)Bs + ((lm * 128 + ks * 64 + lk16) ^ ((lm & 7) << 4)));
    acc4 = __builtin_amdgcn_mfma_f32_16x16x32_bf16(a, b, acc4, 0, 0, 0);
  }
  if (lm < 8) {
    const float pbv = pred_b[lm];
    const int gr0 = row0 + wave * 16 + (lane >> 4) * 4;
    #pragma unroll
    for (int i = 0; i < 4; ++i) {
      const int gr = gr0 + i;
      if (gr < M) out[(size_t)gr * 8 + lm] = acc4[i] + pbv;
    }
  }
}

extern "C" void kernel_launch(void* const* d_in, const int* in_sizes, int n_in,
                              void* d_out, int out_size, void* d_ws, size_t ws_size,
                              hipStream_t stream) {
  const float* feat0  = (const float*)d_in[0];
  const float* feat1  = (const float*)d_in[1];
  const float* fc0_w  = (const float*)d_in[2];
  const float* fc0_b  = (const float*)d_in[3];
  const float* fc1_w  = (const float*)d_in[4];
  const float* fc1_b  = (const float*)d_in[5];
  const float* W1     = (const float*)d_in[6];
  const float* b1     = (const float*)d_in[7];
  const float* W2     = (const float*)d_in[8];
  const float* b2     = (const float*)d_in[9];
  const float* pred_w = (const float*)d_in[10];
  const float* pred_b = (const float*)d_in[11];
  const int*   erow   = (const int*)d_in[12];
  const int*   ecol   = (const int*)d_in[13];
  const float* ew     = (const float*)d_in[14];
  float* out = (float*)d_out;
  const int nE = in_sizes[12];
  const int N = N_NODES;

  char* ws = (char*)d_ws;
  size_t off = 0;
  unsigned short* M0T = (unsigned short*)(ws + off); off += 32768;
  unsigned short* M1T = (unsigned short*)(ws + off); off += 65536;
  unsigned short* W2T = (unsigned short*)(ws + off); off += 16384;
  unsigned short* pwT = (unsigned short*)(ws + off); off += 2048;
  float* cb   = (float*)(ws + off); off += 1024;
  int* gh     = (int*)(ws + off); off += (size_t)NBUCK * NB1 * 4;        // 600 KB
  int* gbase  = (int*)(ws + off); off += (size_t)NB1 * NBUCK * 4;        // 600 KB
  int* bcnt   = (int*)(ws + off); off += 4096;
  uint2* tmp  = (uint2*)(ws + off); off += (size_t)NBUCK * CAP * 8;      // 14.4 MB
  unsigned* spack = (unsigned*)(ws + off); off += (size_t)NBUCK * CAP * 4;  // 7.2 MB
  int2* row_se = (int2*)(ws + off); off += (size_t)N * 8;                // 800 KB
  unsigned short* h  = (unsigned short*)(ws + off); off += (size_t)N * 128 * 2;  // 25.6 MB
  unsigned short* g1 = (unsigned short*)(ws + off); off += (size_t)N * 128 * 2;  // 25.6 MB
  unsigned short* h2 = (unsigned short*)(ws + off); off += (size_t)N * 64 * 2;   // 12.8 MB
  unsigned short* g2 = (unsigned short*)(ws + off); off += (size_t)N * 64 * 2;   // 12.8 MB

  // ---- CSR build: hist -> scan -> scatter -> per-bucket sort (no global atomics) ----
  hipLaunchKernelGGL(hist1_kernel, dim3(NB1), dim3(512), 0, stream, erow, gh, nE);
  hipLaunchKernelGGL(scan_kernel, dim3(1), dim3(1024), 0, stream, gh, gbase, bcnt);
  hipLaunchKernelGGL(scatter1_kernel, dim3(NB1), dim3(512), 0, stream,
                     erow, ecol, ew, gbase, tmp, nE);
  hipLaunchKernelGGL(part2_kernel, dim3(NBUCK), dim3(256), 0, stream,
                     bcnt, tmp, spack, row_se, N);

  // ---- dense pipeline ----
  hipLaunchKernelGGL(prep_small_kernel, dim3(229), dim3(256), 0, stream,
                     fc0_w, fc1_w, fc0_b, fc1_b, W1, W2, pred_w,
                     M0T, M1T, W2T, pwT, cb);
  hipLaunchKernelGGL((mfma_gemm_kernel<128, 128>), dim3((N_TYPE + 63) / 64), dim3(256),
                     0, stream, feat0, M0T, cb, h, N_TYPE);
  hipLaunchKernelGGL((mfma_gemm_kernel<128, 256>), dim3((N_TYPE + 63) / 64), dim3(256),
                     0, stream, feat1, M1T, cb + 128, h + (size_t)N_TYPE * 128, N_TYPE);
  // g1 = bf16(relu(adj @ h + b1))
  hipLaunchKernelGGL(spmm1_kernel, dim3((N * 32 + 255) / 256), dim3(256), 0, stream,
                     h, row_se, spack, b1, g1, N);
  // h2 = bf16(g1 @ W2)
  hipLaunchKernelGGL(gemmA64_kernel, dim3((N + 63) / 64), dim3(256), 0, stream,
                     g1, W2T, h2, N);
  // g2 = bf16(relu(adj @ h2 + b2))
  hipLaunchKernelGGL(spmm2_kernel, dim3((N * 32 + 255) / 256), dim3(256), 0, stream,
                     h2, row_se, spack, b2, g2, N);
  // out = g2 @ pred_w^T + pred_b
  hipLaunchKernelGGL(head_kernel, dim3((N + 63) / 64), dim3(256), 0, stream,
                     g2, pwT, pred_b, out, N);
}

// Round 12
// 224.955 us; speedup vs baseline: 1.0370x; 1.0370x over previous
//
#include <hip/hip_runtime.h>
#include <hip/hip_bf16.h>

#define N_NODES 100000
#define N_TYPE  50000
#define NB1     384        // partition blocks
#define EPB1    4167       // edges per partition block (384*4167 >= 1.6M)
#define NBUCK2  196        // ceil(100000/512) row buckets
#define CAP2    9216       // per-bucket segment capacity (mean ~8163, sd ~90)

typedef short bf16x8 __attribute__((ext_vector_type(8)));
typedef float f32x4  __attribute__((ext_vector_type(4)));
typedef unsigned short u16x4 __attribute__((ext_vector_type(4)));

__device__ inline unsigned short f2bf(float f) {
  union { float f; unsigned u; } x; x.f = f;
  unsigned r = (x.u + 0x7fff + ((x.u >> 16) & 1)) >> 16;  // RNE
  return (unsigned short)r;
}
__device__ inline float bf2f(unsigned short h) {
  union { unsigned u; float f; } x; x.u = ((unsigned)h) << 16;
  return x.f;
}

// ---------------- prep: bf16 transposed weights + combined bias + padded head weights --------
__global__ __launch_bounds__(256) void prep_small_kernel(
    const float* __restrict__ fc0_w, const float* __restrict__ fc1_w,
    const float* __restrict__ fc0_b, const float* __restrict__ fc1_b,
    const float* __restrict__ W1, const float* __restrict__ W2,
    const float* __restrict__ pred_w,
    unsigned short* __restrict__ M0T, unsigned short* __restrict__ M1T,
    unsigned short* __restrict__ W2T, unsigned short* __restrict__ pwT,
    float* __restrict__ cb) {
  int idx = blockIdx.x * 256 + threadIdx.x;
  if (idx < 16384) {                       // M0T[n=128][k=128]
    int i = idx >> 7, j = idx & 127;
    float s = 0.f;
    #pragma unroll 4
    for (int o = 0; o < 128; ++o) s = fmaf(fc0_w[o * 128 + i], W1[o * 128 + j], s);
    M0T[j * 128 + i] = f2bf(s);
  } else if (idx < 49152) {                // M1T[n=128][k=256]
    int r = idx - 16384;
    int i = r >> 7, j = r & 127;
    float s = 0.f;
    #pragma unroll 4
    for (int o = 0; o < 128; ++o) s = fmaf(fc1_w[o * 256 + i], W1[o * 128 + j], s);
    M1T[j * 256 + i] = f2bf(s);
  } else if (idx < 57344) {                // W2T[n=64][k=128]
    int r = idx - 49152;
    int k = r >> 6, n = r & 63;
    W2T[n * 128 + k] = f2bf(W2[k * 64 + n]);
  } else if (idx < 57600) {                // cb[256]
    int r = idx - 57344;
    int t = r >> 7, j = r & 127;
    const float* bb = t ? fc1_b : fc0_b;
    float s = 0.f;
    for (int o = 0; o < 128; ++o) s = fmaf(bb[o], W1[o * 128 + j], s);
    cb[r] = s;
  } else if (idx < 58624) {                // pwT[16][64], rows 8..15 zero-padded
    int r = idx - 57600;
    int n = r >> 6, k = r & 63;
    pwT[r] = (n < 8) ? f2bf(pred_w[n * 64 + k]) : (unsigned short)0;
  }
}

// ---------------- bf16 MFMA GEMM (fp32 A input, feature projections) -------------------------
template <int NC, int KTOT>
__global__ __launch_bounds__(256) void mfma_gemm_kernel(
    const float* __restrict__ A, const unsigned short* __restrict__ BT,
    const float* __restrict__ bc, unsigned short* __restrict__ Cout, int M) {
  constexpr int NREP = NC / 32;
  __shared__ unsigned short As[64 * 128];
  __shared__ unsigned short Bs[NC * 128];

  const int tid = threadIdx.x;
  const int row0 = blockIdx.x * 64;
  const int wave = tid >> 6, lane = tid & 63;
  const int wr = wave >> 1, wc = wave & 1;
  const int lm = lane & 15;
  const int lk16 = (lane >> 4) * 16;

  f32x4 acc[2][NREP];
  #pragma unroll
  for (int i = 0; i < 2; ++i)
    #pragma unroll
    for (int j = 0; j < NREP; ++j) acc[i][j] = (f32x4){0.f, 0.f, 0.f, 0.f};

  for (int kc = 0; kc < KTOT; kc += 128) {
    if (kc) __syncthreads();
    {
      const int r = tid >> 2;
      const int cg = tid & 3;
      int gr = row0 + r; if (gr > M - 1) gr = M - 1;
      const float* arow = A + (size_t)gr * KTOT + kc;
      char* asrow = (char*)As + r * 256;
      const int swz = (r & 7) << 4;
      #pragma unroll
      for (int i = 0; i < 8; ++i) {
        const int c = i * 4 + cg;
        float4 v = *(const float4*)(arow + c * 4);
        u16x4 q = {f2bf(v.x), f2bf(v.y), f2bf(v.z), f2bf(v.w)};
        *(u16x4*)(asrow + ((c * 8) ^ swz)) = q;
      }
    }
    {
      constexpr int CHUNKS = NC * 16;
      #pragma unroll
      for (int i = 0; i < CHUNKS / 256; ++i) {
        const int id = i * 256 + tid;
        const int n = id >> 4, k16 = id & 15;
        const uint4 w = *(const uint4*)((const char*)BT + ((size_t)n * KTOT + kc) * 2 + k16 * 16);
        *(uint4*)((char*)Bs + ((n * 256 + k16 * 16) ^ ((n & 7) << 4))) = w;
      }
    }
    __syncthreads();
    #pragma unroll
    for (int ks = 0; ks < 4; ++ks) {
      bf16x8 a[2];
      #pragma unroll
      for (int m = 0; m < 2; ++m) {
        const int r = wr * 32 + m * 16 + lm;
        a[m] = *(bf16x8*)((char*)As + ((r * 256 + ks * 64 + lk16) ^ ((r & 7) << 4)));
      }
      #pragma unroll
      for (int j = 0; j < NREP; ++j) {
        const int n = wc * (NC / 2) + j * 16 + lm;
        const bf16x8 b = *(bf16x8*)((char*)Bs + ((n * 256 + ks * 64 + lk16) ^ ((n & 7) << 4)));
        acc[0][j] = __builtin_amdgcn_mfma_f32_16x16x32_bf16(a[0], b, acc[0][j], 0, 0, 0);
        acc[1][j] = __builtin_amdgcn_mfma_f32_16x16x32_bf16(a[1], b, acc[1][j], 0, 0, 0);
      }
    }
  }
  #pragma unroll
  for (int m = 0; m < 2; ++m) {
    const int gr0 = row0 + wr * 32 + m * 16 + (lane >> 4) * 4;
    #pragma unroll
    for (int j = 0; j < NREP; ++j) {
      const int col = wc * (NC / 2) + j * 16 + lm;
      const float cbv = bc[col];
      #pragma unroll
      for (int i = 0; i < 4; ++i) {
        const int gr = gr0 + i;
        if (gr < M) Cout[(size_t)gr * NC + col] = f2bf(acc[m][j][i] + cbv);
      }
    }
  }
}

// ---------------- bf16-A GEMM: h2[M][64] = g1_bf16[M][128] @ W2T^T ---------------------------
__global__ __launch_bounds__(256) void gemmA64_kernel(
    const unsigned short* __restrict__ A, const unsigned short* __restrict__ BT,
    unsigned short* __restrict__ Cout, int M) {
  __shared__ unsigned short As[64 * 128];   // 16 KB
  __shared__ unsigned short Bs[64 * 128];   // 16 KB
  const int tid = threadIdx.x;
  const int row0 = blockIdx.x * 64;
  const int wave = tid >> 6, lane = tid & 63;
  const int wr = wave >> 1, wc = wave & 1;
  const int lm = lane & 15, lk16 = (lane >> 4) * 16;
  {
    const int r = tid >> 2, cg = tid & 3;
    int gr = row0 + r; if (gr > M - 1) gr = M - 1;
    const uint4* arow = (const uint4*)(A + (size_t)gr * 128);
    const int swz = (r & 7) << 4;
    #pragma unroll
    for (int i = 0; i < 4; ++i) {
      const int c16 = i * 4 + cg;
      const uint4 w = arow[c16];
      *(uint4*)((char*)As + ((r * 256 + c16 * 16) ^ swz)) = w;
    }
  }
  #pragma unroll
  for (int i = 0; i < 4; ++i) {
    const int id = i * 256 + tid;
    const int n = id >> 4, k16 = id & 15;
    const uint4 w = *(const uint4*)((const char*)BT + n * 256 + k16 * 16);
    *(uint4*)((char*)Bs + ((n * 256 + k16 * 16) ^ ((n & 7) << 4))) = w;
  }
  __syncthreads();
  f32x4 acc[2][2];
  #pragma unroll
  for (int i = 0; i < 2; ++i)
    #pragma unroll
    for (int j = 0; j < 2; ++j) acc[i][j] = (f32x4){0.f, 0.f, 0.f, 0.f};
  #pragma unroll
  for (int ks = 0; ks < 4; ++ks) {
    bf16x8 a[2];
    #pragma unroll
    for (int m = 0; m < 2; ++m) {
      const int r = wr * 32 + m * 16 + lm;
      a[m] = *(bf16x8*)((char*)As + ((r * 256 + ks * 64 + lk16) ^ ((r & 7) << 4)));
    }
    #pragma unroll
    for (int j = 0; j < 2; ++j) {
      const int n = wc * 32 + j * 16 + lm;
      const bf16x8 b = *(bf16x8*)((char*)Bs + ((n * 256 + ks * 64 + lk16) ^ ((n & 7) << 4)));
      acc[0][j] = __builtin_amdgcn_mfma_f32_16x16x32_bf16(a[0], b, acc[0][j], 0, 0, 0);
      acc[1][j] = __builtin_amdgcn_mfma_f32_16x16x32_bf16(a[1], b, acc[1][j], 0, 0, 0);
    }
  }
  #pragma unroll
  for (int m = 0; m < 2; ++m) {
    const int gr0 = row0 + wr * 32 + m * 16 + (lane >> 4) * 4;
    #pragma unroll
    for (int j = 0; j < 2; ++j) {
      const int col = wc * 32 + j * 16 + lm;
      #pragma unroll
      for (int i = 0; i < 4; ++i) {
        const int gr = gr0 + i;
        if (gr < M) Cout[(size_t)gr * 64 + col] = f2bf(acc[m][j][i]);
      }
    }
  }
}

// ---- hist1: per-(block,bucket) histogram; NO global atomics ---------------------------------
__global__ __launch_bounds__(512) void hist1_kernel(
    const int* __restrict__ erow, int* __restrict__ gh, int nE) {
  __shared__ int lh[256];
  const int t = threadIdx.x;
  const int e0 = blockIdx.x * EPB1;
  const int e1 = min(e0 + EPB1, nE);
  for (int i = t; i < 256; i += 512) lh[i] = 0;
  __syncthreads();
  for (int i = e0 + t; i < e1; i += 512) atomicAdd(&lh[erow[i] >> 9], 1);
  __syncthreads();
  for (int i = t; i < NBUCK2; i += 512) gh[i * NB1 + blockIdx.x] = lh[i];
}

// ---- scan: per-bucket serial scan over blocks -> gbase[blk][bucket], bcnt[bucket] -----------
__global__ __launch_bounds__(256) void scan_kernel(
    const int* __restrict__ gh, int* __restrict__ gbase, int* __restrict__ bcnt) {
  const int t = threadIdx.x;
  if (t >= NBUCK2) return;
  int run = t * CAP2;
  for (int blk = 0; blk < NB1; ++blk) {
    gbase[blk * 256 + t] = run;
    run += gh[t * NB1 + blk];
  }
  bcnt[t] = run - t * CAP2;
}

// ---- scatter1: write records to reserved runs (LDS atomics only) ----------------------------
// rec (4B: col<<15|bf16w) and row-in-bucket (2B) go to separate arrays.
__global__ __launch_bounds__(512) void scatter1_kernel(
    const int* __restrict__ erow, const int* __restrict__ ecol,
    const float* __restrict__ ew, const int* __restrict__ gbase,
    unsigned* __restrict__ tmp_rc, unsigned short* __restrict__ tmp_row, int nE) {
  __shared__ int lh[256];
  __shared__ int lbase[256];
  const int t = threadIdx.x;
  const int e0 = blockIdx.x * EPB1;
  const int e1 = min(e0 + EPB1, nE);
  for (int i = t; i < 256; i += 512) {
    lh[i] = 0;
    lbase[i] = (i < NBUCK2) ? gbase[blockIdx.x * 256 + i] : 0;
  }
  __syncthreads();
  for (int i = e0 + t; i < e1; i += 512) {
    const int r = erow[i];
    const int b = r >> 9;
    const int pos = lbase[b] + atomicAdd(&lh[b], 1);
    const unsigned short bw = f2bf(ew[i]);             // w in [0,1): sign 0, fits 15 bits
    tmp_rc[pos] = ((unsigned)ecol[i] << 15) | (unsigned)bw;
    tmp_row[pos] = (unsigned short)(r & 511);
  }
}

// ---- part2: per-bucket counting sort into row order; emits row_se ---------------------------
__global__ __launch_bounds__(512) void part2_kernel(
    const int* __restrict__ bcnt, const unsigned* __restrict__ tmp_rc,
    const unsigned short* __restrict__ tmp_row,
    unsigned* __restrict__ spack, int2* __restrict__ row_se, int N) {
  __shared__ int hist[512];
  __shared__ int scn[512];
  __shared__ int cur[512];
  const int b = blockIdx.x;
  const int r0 = b << 9;
  const int t = threadIdx.x;
  const int base = b * CAP2;
  const int cnt = bcnt[b];
  const unsigned* rc = tmp_rc + base;
  const unsigned short* rw = tmp_row + base;
  hist[t] = 0;
  __syncthreads();
  for (int i = t; i < cnt; i += 512)
    atomicAdd(&hist[rw[i]], 1);
  __syncthreads();
  const int v = hist[t];
  scn[t] = v;
  __syncthreads();
  #pragma unroll
  for (int off = 1; off < 512; off <<= 1) {
    int y = (t >= off) ? scn[t - off] : 0;
    __syncthreads();
    scn[t] += y;
    __syncthreads();
  }
  const int excl = base + scn[t] - v;
  const int r = r0 + t;
  if (r < N) row_se[r] = make_int2(excl, excl + v);
  cur[t] = excl;
  __syncthreads();
  for (int i = t; i < cnt; i += 512) {
    const int pos = atomicAdd(&cur[rw[i]], 1);
    spack[pos] = rc[i];
  }
}

// ---- spmm1: g1 = bf16(relu(adj @ h + b1)); 32 lanes/row, u16x4 (8B) gathers, unroll 4 -------
__global__ __launch_bounds__(256) void spmm1_kernel(
    const unsigned short* __restrict__ h, const int2* __restrict__ row_se,
    const unsigned* __restrict__ spack, const float* __restrict__ b1,
    unsigned short* __restrict__ g1, int M) {
  const int r = (blockIdx.x * 256 + threadIdx.x) >> 5;
  const int lane = threadIdx.x & 31;
  if (r >= M) return;
  const int2 se = row_se[r];
  f32x4 acc = (f32x4){0.f, 0.f, 0.f, 0.f};
  int j = se.x;
  for (; j + 3 < se.y; j += 4) {
    const unsigned rc0 = spack[j], rc1 = spack[j + 1];
    const unsigned rc2 = spack[j + 2], rc3 = spack[j + 3];
    const u16x4 v0 = *(const u16x4*)(h + (size_t)(rc0 >> 15) * 128 + lane * 4);
    const u16x4 v1 = *(const u16x4*)(h + (size_t)(rc1 >> 15) * 128 + lane * 4);
    const u16x4 v2 = *(const u16x4*)(h + (size_t)(rc2 >> 15) * 128 + lane * 4);
    const u16x4 v3 = *(const u16x4*)(h + (size_t)(rc3 >> 15) * 128 + lane * 4);
    const float w0 = bf2f((unsigned short)(rc0 & 0x7fff));
    const float w1 = bf2f((unsigned short)(rc1 & 0x7fff));
    const float w2 = bf2f((unsigned short)(rc2 & 0x7fff));
    const float w3 = bf2f((unsigned short)(rc3 & 0x7fff));
    #pragma unroll
    for (int k = 0; k < 4; ++k) {
      acc[k] = fmaf(bf2f(v0[k]), w0, acc[k]);
      acc[k] = fmaf(bf2f(v1[k]), w1, acc[k]);
      acc[k] = fmaf(bf2f(v2[k]), w2, acc[k]);
      acc[k] = fmaf(bf2f(v3[k]), w3, acc[k]);
    }
  }
  for (; j < se.y; ++j) {
    const unsigned rc0 = spack[j];
    const u16x4 v0 = *(const u16x4*)(h + (size_t)(rc0 >> 15) * 128 + lane * 4);
    const float w0 = bf2f((unsigned short)(rc0 & 0x7fff));
    #pragma unroll
    for (int k = 0; k < 4; ++k) acc[k] = fmaf(bf2f(v0[k]), w0, acc[k]);
  }
  const float4 bb = *(const float4*)(b1 + lane * 4);
  u16x4 o;
  o[0] = f2bf(fmaxf(acc[0] + bb.x, 0.f));
  o[1] = f2bf(fmaxf(acc[1] + bb.y, 0.f));
  o[2] = f2bf(fmaxf(acc[2] + bb.z, 0.f));
  o[3] = f2bf(fmaxf(acc[3] + bb.w, 0.f));
  *(u16x4*)(g1 + (size_t)r * 128 + lane * 4) = o;
}

// ---- spmm2: g2 = bf16(relu(adj @ h2 + b2)); 32 lanes/row, ushort2 (4B) gathers --------------
__global__ __launch_bounds__(256) void spmm2_kernel(
    const unsigned short* __restrict__ h2, const int2* __restrict__ row_se,
    const unsigned* __restrict__ spack, const float* __restrict__ b2,
    unsigned short* __restrict__ g2, int M) {
  const int r = (blockIdx.x * 256 + threadIdx.x) >> 5;
  const int lane = threadIdx.x & 31;
  if (r >= M) return;
  const int2 se = row_se[r];
  float2 acc = make_float2(0.f, 0.f);
  int j = se.x;
  for (; j + 3 < se.y; j += 4) {
    const unsigned rc0 = spack[j], rc1 = spack[j + 1];
    const unsigned rc2 = spack[j + 2], rc3 = spack[j + 3];
    const ushort2 v0 = *(const ushort2*)(h2 + (size_t)(rc0 >> 15) * 64 + lane * 2);
    const ushort2 v1 = *(const ushort2*)(h2 + (size_t)(rc1 >> 15) * 64 + lane * 2);
    const ushort2 v2 = *(const ushort2*)(h2 + (size_t)(rc2 >> 15) * 64 + lane * 2);
    const ushort2 v3 = *(const ushort2*)(h2 + (size_t)(rc3 >> 15) * 64 + lane * 2);
    const float w0 = bf2f((unsigned short)(rc0 & 0x7fff));
    const float w1 = bf2f((unsigned short)(rc1 & 0x7fff));
    const float w2 = bf2f((unsigned short)(rc2 & 0x7fff));
    const float w3 = bf2f((unsigned short)(rc3 & 0x7fff));
    acc.x = fmaf(bf2f(v0.x), w0, acc.x);
    acc.y = fmaf(bf2f(v0.y), w0, acc.y);
    acc.x = fmaf(bf2f(v1.x), w1, acc.x);
    acc.y = fmaf(bf2f(v1.y), w1, acc.y);
    acc.x = fmaf(bf2f(v2.x), w2, acc.x);
    acc.y = fmaf(bf2f(v2.y), w2, acc.y);
    acc.x = fmaf(bf2f(v3.x), w3, acc.x);
    acc.y = fmaf(bf2f(v3.y), w3, acc.y);
  }
  for (; j < se.y; ++j) {
    const unsigned rc0 = spack[j];
    const ushort2 v0 = *(const ushort2*)(h2 + (size_t)(rc0 >> 15) * 64 + lane * 2);
    const float w0 = bf2f((unsigned short)(rc0 & 0x7fff));
    acc.x = fmaf(bf2f(v0.x), w0, acc.x);
    acc.y = fmaf(bf2f(v0.y), w0, acc.y);
  }
  ushort2 o;
  o.x = f2bf(fmaxf(acc.x + b2[lane * 2], 0.f));
  o.y = f2bf(fmaxf(acc.y + b2[lane * 2 + 1], 0.f));
  *(ushort2*)(g2 + (size_t)r * 64 + lane * 2) = o;
}

// ---- head: out[M][8] = g2[M][64] @ pwT^T + pred_b (MFMA, 64 rows/block) ---------------------
__global__ __launch_bounds__(256) void head_kernel(
    const unsigned short* __restrict__ g2, const unsigned short* __restrict__ pwT,
    const float* __restrict__ pred_b, float* __restrict__ out, int M) {
  __shared__ unsigned short As[64 * 64];    // 8 KB
  __shared__ unsigned short Bs[16 * 64];    // 2 KB
  const int tid = threadIdx.x;
  const int wave = tid >> 6, lane = tid & 63;
  const int row0 = blockIdx.x * 64;
  if (tid < 128) {
    const int n = tid >> 3, k16 = tid & 7;
    const uint4 w = *(const uint4*)((const char*)pwT + n * 128 + k16 * 16);
    *(uint4*)((char*)Bs + ((n * 128 + k16 * 16) ^ ((n & 7) << 4))) = w;
  }
  #pragma unroll
  for (int i = 0; i < 2; ++i) {
    const int id = i * 256 + tid;
    const int rr = id >> 3, k16 = id & 7;
    int gr = row0 + rr; if (gr > M - 1) gr = M - 1;
    const uint4 w = *(const uint4*)(g2 + (size_t)gr * 64 + k16 * 8);
    *(uint4*)((char*)As + ((rr * 128 + k16 * 16) ^ ((rr & 7) << 4))) = w;
  }
  __syncthreads();
  const int lm = lane & 15, lk16 = (lane >> 4) * 16;
  f32x4 acc4 = (f32x4){0.f, 0.f, 0.f, 0.f};
  #pragma unroll
  for (int ks = 0; ks < 2; ++ks) {
    const int rrow = wave * 16 + lm;
    const bf16x8 a = *(bf16x8*)((char*)As + ((rrow * 128 + ks * 64 + lk16) ^ ((rrow & 7) << 4)));
    const bf16x8 b = *(bf16x8*)((char*)Bs + ((lm * 128 + ks * 64 + lk16) ^ ((lm & 7) << 4)));
    acc4 = __builtin_amdgcn_mfma_f32_16x16x32_bf16(a, b, acc4, 0, 0, 0);
  }
  if (lm < 8) {
    const float pbv = pred_b[lm];
    const int gr0 = row0 + wave * 16 + (lane >> 4) * 4;
    #pragma unroll
    for (int i = 0; i < 4; ++i) {
      const int gr = gr0 + i;
      if (gr < M) out[(size_t)gr * 8 + lm] = acc4[i] + pbv;
    }
  }
}

extern "C" void kernel_launch(void* const* d_in, const int* in_sizes, int n_in,
                              void* d_out, int out_size, void* d_ws, size_t ws_size,
                              hipStream_t stream) {
  const float* feat0  = (const float*)d_in[0];
  const float* feat1  = (const float*)d_in[1];
  const float* fc0_w  = (const float*)d_in[2];
  const float* fc0_b  = (const float*)d_in[3];
  const float* fc1_w  = (const float*)d_in[4];
  const float* fc1_b  = (const float*)d_in[5];
  const float* W1     = (const float*)d_in[6];
  const float* b1     = (const float*)d_in[7];
  const float* W2     = (const float*)d_in[8];
  const float* b2     = (const float*)d_in[9];
  const float* pred_w = (const float*)d_in[10];
  const float* pred_b = (const float*)d_in[11];
  const int*   erow   = (const int*)d_in[12];
  const int*   ecol   = (const int*)d_in[13];
  const float* ew     = (const float*)d_in[14];
  float* out = (float*)d_out;
  const int nE = in_sizes[12];
  const int N = N_NODES;

  char* ws = (char*)d_ws;
  size_t off = 0;
  unsigned short* M0T = (unsigned short*)(ws + off); off += 32768;
  unsigned short* M1T = (unsigned short*)(ws + off); off += 65536;
  unsigned short* W2T = (unsigned short*)(ws + off); off += 16384;
  unsigned short* pwT = (unsigned short*)(ws + off); off += 2048;
  float* cb   = (float*)(ws + off); off += 1024;
  int* gh     = (int*)(ws + off); off += (size_t)NBUCK2 * NB1 * 4;       // 301 KB
  int* gbase  = (int*)(ws + off); off += (size_t)NB1 * 256 * 4;          // 393 KB
  int* bcnt   = (int*)(ws + off); off += 1024;
  unsigned* tmp_rc = (unsigned*)(ws + off); off += (size_t)NBUCK2 * CAP2 * 4;       // 7.2 MB
  unsigned short* tmp_row = (unsigned short*)(ws + off); off += (size_t)NBUCK2 * CAP2 * 2; // 3.6 MB
  unsigned* spack = (unsigned*)(ws + off); off += (size_t)NBUCK2 * CAP2 * 4;  // 7.2 MB
  int2* row_se = (int2*)(ws + off); off += (size_t)N * 8;                // 800 KB
  unsigned short* h  = (unsigned short*)(ws + off); off += (size_t)N * 128 * 2;  // 25.6 MB
  unsigned short* g1 = (unsigned short*)(ws + off); off += (size_t)N * 128 * 2;  // 25.6 MB
  unsigned short* h2 = (unsigned short*)(ws + off); off += (size_t)N * 64 * 2;   // 12.8 MB
  unsigned short* g2 = (unsigned short*)(ws + off); off += (size_t)N * 64 * 2;   // 12.8 MB

  // ---- CSR build: hist -> scan -> scatter -> per-bucket sort (no global atomics) ----
  hipLaunchKernelGGL(hist1_kernel, dim3(NB1), dim3(512), 0, stream, erow, gh, nE);
  hipLaunchKernelGGL(scan_kernel, dim3(1), dim3(256), 0, stream, gh, gbase, bcnt);
  hipLaunchKernelGGL(scatter1_kernel, dim3(NB1), dim3(512), 0, stream,
                     erow, ecol, ew, gbase, tmp_rc, tmp_row, nE);
  hipLaunchKernelGGL(part2_kernel, dim3(NBUCK2), dim3(512), 0, stream,
                     bcnt, tmp_rc, tmp_row, spack, row_se, N);

  // ---- dense pipeline ----
  hipLaunchKernelGGL(prep_small_kernel, dim3(229), dim3(256), 0, stream,
                     fc0_w, fc1_w, fc0_b, fc1_b, W1, W2, pred_w,
                     M0T, M1T, W2T, pwT, cb);
  hipLaunchKernelGGL((mfma_gemm_kernel<128, 128>), dim3((N_TYPE + 63) / 64), dim3(256),
                     0, stream, feat0, M0T, cb, h, N_TYPE);
  hipLaunchKernelGGL((mfma_gemm_kernel<128, 256>), dim3((N_TYPE + 63) / 64), dim3(256),
                     0, stream, feat1, M1T, cb + 128, h + (size_t)N_TYPE * 128, N_TYPE);
  // g1 = bf16(relu(adj @ h + b1))
  hipLaunchKernelGGL(spmm1_kernel, dim3((N * 32 + 255) / 256), dim3(256), 0, stream,
                     h, row_se, spack, b1, g1, N);
  // h2 = bf16(g1 @ W2)
  hipLaunchKernelGGL(gemmA64_kernel, dim3((N + 63) / 64), dim3(256), 0, stream,
                     g1, W2T, h2, N);
  // g2 = bf16(relu(adj @ h2 + b2))
  hipLaunchKernelGGL(spmm2_kernel, dim3((N * 32 + 255) / 256), dim3(256), 0, stream,
                     h2, row_se, spack, b2, g2, N);
  // out = g2 @ pred_w^T + pred_b
  hipLaunchKernelGGL(head_kernel, dim3((N + 63) / 64), dim3(256), 0, stream,
                     g2, pwT, pred_b, out, N);
}

// Round 13
// 208.553 us; speedup vs baseline: 1.1186x; 1.0786x over previous
//
#include <hip/hip_runtime.h>
#include <hip/hip_bf16.h>

#define N_NODES 100000
#define N_TYPE  50000
#define NB1     192        // partition blocks
#define EPB1    8334       // edges per partition block (192*8334 >= 1.6M)
#define NBUCK2  196        // ceil(100000/512) row buckets
#define CAP2    9216       // per-bucket segment capacity (mean ~8163, sd ~90)

typedef short bf16x8 __attribute__((ext_vector_type(8)));
typedef float f32x4  __attribute__((ext_vector_type(4)));
typedef unsigned short u16x4 __attribute__((ext_vector_type(4)));

__device__ inline unsigned short f2bf(float f) {
  union { float f; unsigned u; } x; x.f = f;
  unsigned r = (x.u + 0x7fff + ((x.u >> 16) & 1)) >> 16;  // RNE
  return (unsigned short)r;
}
__device__ inline float bf2f(unsigned short h) {
  union { unsigned u; float f; } x; x.u = ((unsigned)h) << 16;
  return x.f;
}

// ---------------- prep: bf16 transposed weights + combined bias + padded head weights --------
__global__ __launch_bounds__(256) void prep_small_kernel(
    const float* __restrict__ fc0_w, const float* __restrict__ fc1_w,
    const float* __restrict__ fc0_b, const float* __restrict__ fc1_b,
    const float* __restrict__ W1, const float* __restrict__ W2,
    const float* __restrict__ pred_w,
    unsigned short* __restrict__ M0T, unsigned short* __restrict__ M1T,
    unsigned short* __restrict__ W2T, unsigned short* __restrict__ pwT,
    float* __restrict__ cb) {
  int idx = blockIdx.x * 256 + threadIdx.x;
  if (idx < 16384) {                       // M0T[n=128][k=128]
    int i = idx >> 7, j = idx & 127;
    float s = 0.f;
    #pragma unroll 4
    for (int o = 0; o < 128; ++o) s = fmaf(fc0_w[o * 128 + i], W1[o * 128 + j], s);
    M0T[j * 128 + i] = f2bf(s);
  } else if (idx < 49152) {                // M1T[n=128][k=256]
    int r = idx - 16384;
    int i = r >> 7, j = r & 127;
    float s = 0.f;
    #pragma unroll 4
    for (int o = 0; o < 128; ++o) s = fmaf(fc1_w[o * 256 + i], W1[o * 128 + j], s);
    M1T[j * 256 + i] = f2bf(s);
  } else if (idx < 57344) {                // W2T[n=64][k=128]
    int r = idx - 49152;
    int k = r >> 6, n = r & 63;
    W2T[n * 128 + k] = f2bf(W2[k * 64 + n]);
  } else if (idx < 57600) {                // cb[256]
    int r = idx - 57344;
    int t = r >> 7, j = r & 127;
    const float* bb = t ? fc1_b : fc0_b;
    float s = 0.f;
    for (int o = 0; o < 128; ++o) s = fmaf(bb[o], W1[o * 128 + j], s);
    cb[r] = s;
  } else if (idx < 58624) {                // pwT[16][64], rows 8..15 zero-padded
    int r = idx - 57600;
    int n = r >> 6, k = r & 63;
    pwT[r] = (n < 8) ? f2bf(pred_w[n * 64 + k]) : (unsigned short)0;
  }
}

// ---------------- bf16 MFMA GEMM (fp32 A input, feature projections) -------------------------
template <int NC, int KTOT>
__global__ __launch_bounds__(256) void mfma_gemm_kernel(
    const float* __restrict__ A, const unsigned short* __restrict__ BT,
    const float* __restrict__ bc, unsigned short* __restrict__ Cout, int M) {
  constexpr int NREP = NC / 32;
  __shared__ unsigned short As[64 * 128];
  __shared__ unsigned short Bs[NC * 128];

  const int tid = threadIdx.x;
  const int row0 = blockIdx.x * 64;
  const int wave = tid >> 6, lane = tid & 63;
  const int wr = wave >> 1, wc = wave & 1;
  const int lm = lane & 15;
  const int lk16 = (lane >> 4) * 16;

  f32x4 acc[2][NREP];
  #pragma unroll
  for (int i = 0; i < 2; ++i)
    #pragma unroll
    for (int j = 0; j < NREP; ++j) acc[i][j] = (f32x4){0.f, 0.f, 0.f, 0.f};

  for (int kc = 0; kc < KTOT; kc += 128) {
    if (kc) __syncthreads();
    {
      const int r = tid >> 2;
      const int cg = tid & 3;
      int gr = row0 + r; if (gr > M - 1) gr = M - 1;
      const float* arow = A + (size_t)gr * KTOT + kc;
      char* asrow = (char*)As + r * 256;
      const int swz = (r & 7) << 4;
      #pragma unroll
      for (int i = 0; i < 8; ++i) {
        const int c = i * 4 + cg;
        float4 v = *(const float4*)(arow + c * 4);
        u16x4 q = {f2bf(v.x), f2bf(v.y), f2bf(v.z), f2bf(v.w)};
        *(u16x4*)(asrow + ((c * 8) ^ swz)) = q;
      }
    }
    {
      constexpr int CHUNKS = NC * 16;
      #pragma unroll
      for (int i = 0; i < CHUNKS / 256; ++i) {
        const int id = i * 256 + tid;
        const int n = id >> 4, k16 = id & 15;
        const uint4 w = *(const uint4*)((const char*)BT + ((size_t)n * KTOT + kc) * 2 + k16 * 16);
        *(uint4*)((char*)Bs + ((n * 256 + k16 * 16) ^ ((n & 7) << 4))) = w;
      }
    }
    __syncthreads();
    #pragma unroll
    for (int ks = 0; ks < 4; ++ks) {
      bf16x8 a[2];
      #pragma unroll
      for (int m = 0; m < 2; ++m) {
        const int r = wr * 32 + m * 16 + lm;
        a[m] = *(bf16x8*)((char*)As + ((r * 256 + ks * 64 + lk16) ^ ((r & 7) << 4)));
      }
      #pragma unroll
      for (int j = 0; j < NREP; ++j) {
        const int n = wc * (NC / 2) + j * 16 + lm;
        const bf16x8 b = *(bf16x8*)((char*)Bs + ((n * 256 + ks * 64 + lk16) ^ ((n & 7) << 4)));
        acc[0][j] = __builtin_amdgcn_mfma_f32_16x16x32_bf16(a[0], b, acc[0][j], 0, 0, 0);
        acc[1][j] = __builtin_amdgcn_mfma_f32_16x16x32_bf16(a[1], b, acc[1][j], 0, 0, 0);
      }
    }
  }
  #pragma unroll
  for (int m = 0; m < 2; ++m) {
    const int gr0 = row0 + wr * 32 + m * 16 + (lane >> 4) * 4;
    #pragma unroll
    for (int j = 0; j < NREP; ++j) {
      const int col = wc * (NC / 2) + j * 16 + lm;
      const float cbv = bc[col];
      #pragma unroll
      for (int i = 0; i < 4; ++i) {
        const int gr = gr0 + i;
        if (gr < M) Cout[(size_t)gr * NC + col] = f2bf(acc[m][j][i] + cbv);
      }
    }
  }
}

// ---------------- bf16-A GEMM: h2[M][64] = g1_bf16[M][128] @ W2T^T ---------------------------
__global__ __launch_bounds__(256) void gemmA64_kernel(
    const unsigned short* __restrict__ A, const unsigned short* __restrict__ BT,
    unsigned short* __restrict__ Cout, int M) {
  __shared__ unsigned short As[64 * 128];   // 16 KB
  __shared__ unsigned short Bs[64 * 128];   // 16 KB
  const int tid = threadIdx.x;
  const int row0 = blockIdx.x * 64;
  const int wave = tid >> 6, lane = tid & 63;
  const int wr = wave >> 1, wc = wave & 1;
  const int lm = lane & 15, lk16 = (lane >> 4) * 16;
  {
    const int r = tid >> 2, cg = tid & 3;
    int gr = row0 + r; if (gr > M - 1) gr = M - 1;
    const uint4* arow = (const uint4*)(A + (size_t)gr * 128);
    const int swz = (r & 7) << 4;
    #pragma unroll
    for (int i = 0; i < 4; ++i) {
      const int c16 = i * 4 + cg;
      const uint4 w = arow[c16];
      *(uint4*)((char*)As + ((r * 256 + c16 * 16) ^ swz)) = w;
    }
  }
  #pragma unroll
  for (int i = 0; i < 4; ++i) {
    const int id = i * 256 + tid;
    const int n = id >> 4, k16 = id & 15;
    const uint4 w = *(const uint4*)((const char*)BT + n * 256 + k16 * 16);
    *(uint4*)((char*)Bs + ((n * 256 + k16 * 16) ^ ((n & 7) << 4))) = w;
  }
  __syncthreads();
  f32x4 acc[2][2];
  #pragma unroll
  for (int i = 0; i < 2; ++i)
    #pragma unroll
    for (int j = 0; j < 2; ++j) acc[i][j] = (f32x4){0.f, 0.f, 0.f, 0.f};
  #pragma unroll
  for (int ks = 0; ks < 4; ++ks) {
    bf16x8 a[2];
    #pragma unroll
    for (int m = 0; m < 2; ++m) {
      const int r = wr * 32 + m * 16 + lm;
      a[m] = *(bf16x8*)((char*)As + ((r * 256 + ks * 64 + lk16) ^ ((r & 7) << 4)));
    }
    #pragma unroll
    for (int j = 0; j < 2; ++j) {
      const int n = wc * 32 + j * 16 + lm;
      const bf16x8 b = *(bf16x8*)((char*)Bs + ((n * 256 + ks * 64 + lk16) ^ ((n & 7) << 4)));
      acc[0][j] = __builtin_amdgcn_mfma_f32_16x16x32_bf16(a[0], b, acc[0][j], 0, 0, 0);
      acc[1][j] = __builtin_amdgcn_mfma_f32_16x16x32_bf16(a[1], b, acc[1][j], 0, 0, 0);
    }
  }
  #pragma unroll
  for (int m = 0; m < 2; ++m) {
    const int gr0 = row0 + wr * 32 + m * 16 + (lane >> 4) * 4;
    #pragma unroll
    for (int j = 0; j < 2; ++j) {
      const int col = wc * 32 + j * 16 + lm;
      #pragma unroll
      for (int i = 0; i < 4; ++i) {
        const int gr = gr0 + i;
        if (gr < M) Cout[(size_t)gr * 64 + col] = f2bf(acc[m][j][i]);
      }
    }
  }
}

// ---- hist1: per-(block,bucket) histogram; NO global atomics ---------------------------------
__global__ __launch_bounds__(512) void hist1_kernel(
    const int* __restrict__ erow, int* __restrict__ gh, int nE) {
  __shared__ int lh[256];
  const int t = threadIdx.x;
  const int e0 = blockIdx.x * EPB1;
  const int e1 = min(e0 + EPB1, nE);
  for (int i = t; i < 256; i += 512) lh[i] = 0;
  __syncthreads();
  for (int i = e0 + t; i < e1; i += 512) atomicAdd(&lh[erow[i] >> 9], 1);
  __syncthreads();
  for (int i = t; i < NBUCK2; i += 512) gh[i * NB1 + blockIdx.x] = lh[i];
}

// ---- scan: per-bucket serial scan over blocks -> gbase[blk][bucket], bcnt[bucket] -----------
__global__ __launch_bounds__(256) void scan_kernel(
    const int* __restrict__ gh, int* __restrict__ gbase, int* __restrict__ bcnt) {
  const int t = threadIdx.x;
  if (t >= NBUCK2) return;
  int run = t * CAP2;
  for (int blk = 0; blk < NB1; ++blk) {
    gbase[blk * 256 + t] = run;
    run += gh[t * NB1 + blk];
  }
  bcnt[t] = run - t * CAP2;
}

// ---- scatter1: write records to reserved runs (LDS atomics only) ----------------------------
__global__ __launch_bounds__(512) void scatter1_kernel(
    const int* __restrict__ erow, const int* __restrict__ ecol,
    const float* __restrict__ ew, const int* __restrict__ gbase,
    uint2* __restrict__ tmp, int nE) {
  __shared__ int lh[256];
  __shared__ int lbase[256];
  const int t = threadIdx.x;
  const int e0 = blockIdx.x * EPB1;
  const int e1 = min(e0 + EPB1, nE);
  for (int i = t; i < 256; i += 512) {
    lh[i] = 0;
    lbase[i] = (i < NBUCK2) ? gbase[blockIdx.x * 256 + i] : 0;
  }
  __syncthreads();
  for (int i = e0 + t; i < e1; i += 512) {
    const int r = erow[i];
    const int b = r >> 9;
    const int pos = lbase[b] + atomicAdd(&lh[b], 1);
    const unsigned short bw = f2bf(ew[i]);             // w in [0,1): sign 0, fits 15 bits
    const unsigned rec = ((unsigned)ecol[i] << 15) | (unsigned)bw;
    tmp[pos] = make_uint2(rec, (unsigned)r);
  }
}

// ---- part2: per-bucket counting sort into row order; emits row_se ---------------------------
__global__ __launch_bounds__(512) void part2_kernel(
    const int* __restrict__ bcnt, const uint2* __restrict__ tmp,
    unsigned* __restrict__ spack, int2* __restrict__ row_se, int N) {
  __shared__ int hist[512];
  __shared__ int scn[512];
  __shared__ int cur[512];
  const int b = blockIdx.x;
  const int r0 = b << 9;
  const int t = threadIdx.x;
  const int base = b * CAP2;
  const int cnt = bcnt[b];
  const uint2* rec = tmp + base;
  hist[t] = 0;
  __syncthreads();
  for (int i = t; i < cnt; i += 512)
    atomicAdd(&hist[(int)rec[i].y - r0], 1);
  __syncthreads();
  const int v = hist[t];
  scn[t] = v;
  __syncthreads();
  #pragma unroll
  for (int off = 1; off < 512; off <<= 1) {
    int y = (t >= off) ? scn[t - off] : 0;
    __syncthreads();
    scn[t] += y;
    __syncthreads();
  }
  const int excl = base + scn[t] - v;
  const int r = r0 + t;
  if (r < N) row_se[r] = make_int2(excl, excl + v);
  cur[t] = excl;
  __syncthreads();
  for (int i = t; i < cnt; i += 512) {
    const uint2 rc = rec[i];
    const int pos = atomicAdd(&cur[(int)rc.y - r0], 1);
    spack[pos] = rc.x;
  }
}

// ---- spmm1: g1 = bf16(relu(adj @ h + b1)); 32 lanes/row, u16x4 (8B) gathers, unroll 4 -------
__global__ __launch_bounds__(256) void spmm1_kernel(
    const unsigned short* __restrict__ h, const int2* __restrict__ row_se,
    const unsigned* __restrict__ spack, const float* __restrict__ b1,
    unsigned short* __restrict__ g1, int M) {
  const int r = (blockIdx.x * 256 + threadIdx.x) >> 5;
  const int lane = threadIdx.x & 31;
  if (r >= M) return;
  const int2 se = row_se[r];
  f32x4 acc = (f32x4){0.f, 0.f, 0.f, 0.f};
  int j = se.x;
  for (; j + 3 < se.y; j += 4) {
    const unsigned rc0 = spack[j], rc1 = spack[j + 1];
    const unsigned rc2 = spack[j + 2], rc3 = spack[j + 3];
    const u16x4 v0 = *(const u16x4*)(h + (size_t)(rc0 >> 15) * 128 + lane * 4);
    const u16x4 v1 = *(const u16x4*)(h + (size_t)(rc1 >> 15) * 128 + lane * 4);
    const u16x4 v2 = *(const u16x4*)(h + (size_t)(rc2 >> 15) * 128 + lane * 4);
    const u16x4 v3 = *(const u16x4*)(h + (size_t)(rc3 >> 15) * 128 + lane * 4);
    const float w0 = bf2f((unsigned short)(rc0 & 0x7fff));
    const float w1 = bf2f((unsigned short)(rc1 & 0x7fff));
    const float w2 = bf2f((unsigned short)(rc2 & 0x7fff));
    const float w3 = bf2f((unsigned short)(rc3 & 0x7fff));
    #pragma unroll
    for (int k = 0; k < 4; ++k) {
      acc[k] = fmaf(bf2f(v0[k]), w0, acc[k]);
      acc[k] = fmaf(bf2f(v1[k]), w1, acc[k]);
      acc[k] = fmaf(bf2f(v2[k]), w2, acc[k]);
      acc[k] = fmaf(bf2f(v3[k]), w3, acc[k]);
    }
  }
  for (; j < se.y; ++j) {
    const unsigned rc0 = spack[j];
    const u16x4 v0 = *(const u16x4*)(h + (size_t)(rc0 >> 15) * 128 + lane * 4);
    const float w0 = bf2f((unsigned short)(rc0 & 0x7fff));
    #pragma unroll
    for (int k = 0; k < 4; ++k) acc[k] = fmaf(bf2f(v0[k]), w0, acc[k]);
  }
  const float4 bb = *(const float4*)(b1 + lane * 4);
  u16x4 o;
  o[0] = f2bf(fmaxf(acc[0] + bb.x, 0.f));
  o[1] = f2bf(fmaxf(acc[1] + bb.y, 0.f));
  o[2] = f2bf(fmaxf(acc[2] + bb.z, 0.f));
  o[3] = f2bf(fmaxf(acc[3] + bb.w, 0.f));
  *(u16x4*)(g1 + (size_t)r * 128 + lane * 4) = o;
}

// ---- spmm2: g2 = bf16(relu(adj @ h2 + b2)); 32 lanes/row, ushort2 (4B) gathers --------------
__global__ __launch_bounds__(256) void spmm2_kernel(
    const unsigned short* __restrict__ h2, const int2* __restrict__ row_se,
    const unsigned* __restrict__ spack, const float* __restrict__ b2,
    unsigned short* __restrict__ g2, int M) {
  const int r = (blockIdx.x * 256 + threadIdx.x) >> 5;
  const int lane = threadIdx.x & 31;
  if (r >= M) return;
  const int2 se = row_se[r];
  float2 acc = make_float2(0.f, 0.f);
  int j = se.x;
  for (; j + 3 < se.y; j += 4) {
    const unsigned rc0 = spack[j], rc1 = spack[j + 1];
    const unsigned rc2 = spack[j + 2], rc3 = spack[j + 3];
    const ushort2 v0 = *(const ushort2*)(h2 + (size_t)(rc0 >> 15) * 64 + lane * 2);
    const ushort2 v1 = *(const ushort2*)(h2 + (size_t)(rc1 >> 15) * 64 + lane * 2);
    const ushort2 v2 = *(const ushort2*)(h2 + (size_t)(rc2 >> 15) * 64 + lane * 2);
    const ushort2 v3 = *(const ushort2*)(h2 + (size_t)(rc3 >> 15) * 64 + lane * 2);
    const float w0 = bf2f((unsigned short)(rc0 & 0x7fff));
    const float w1 = bf2f((unsigned short)(rc1 & 0x7fff));
    const float w2 = bf2f((unsigned short)(rc2 & 0x7fff));
    const float w3 = bf2f((unsigned short)(rc3 & 0x7fff));
    acc.x = fmaf(bf2f(v0.x), w0, acc.x);
    acc.y = fmaf(bf2f(v0.y), w0, acc.y);
    acc.x = fmaf(bf2f(v1.x), w1, acc.x);
    acc.y = fmaf(bf2f(v1.y), w1, acc.y);
    acc.x = fmaf(bf2f(v2.x), w2, acc.x);
    acc.y = fmaf(bf2f(v2.y), w2, acc.y);
    acc.x = fmaf(bf2f(v3.x), w3, acc.x);
    acc.y = fmaf(bf2f(v3.y), w3, acc.y);
  }
  for (; j < se.y; ++j) {
    const unsigned rc0 = spack[j];
    const ushort2 v0 = *(const ushort2*)(h2 + (size_t)(rc0 >> 15) * 64 + lane * 2);
    const float w0 = bf2f((unsigned short)(rc0 & 0x7fff));
    acc.x = fmaf(bf2f(v0.x), w0, acc.x);
    acc.y = fmaf(bf2f(v0.y), w0, acc.y);
  }
  ushort2 o;
  o.x = f2bf(fmaxf(acc.x + b2[lane * 2], 0.f));
  o.y = f2bf(fmaxf(acc.y + b2[lane * 2 + 1], 0.f));
  *(ushort2*)(g2 + (size_t)r * 64 + lane * 2) = o;
}

// ---- head: out[M][8] = g2[M][64] @ pwT^T + pred_b (MFMA, 64 rows/block) ---------------------
__global__ __launch_bounds__(256) void head_kernel(
    const unsigned short* __restrict__ g2, const unsigned short* __restrict__ pwT,
    const float* __restrict__ pred_b, float* __restrict__ out, int M) {
  __shared__ unsigned short As[64 * 64];    // 8 KB
  __shared__ unsigned short Bs[16 * 64];    // 2 KB
  const int tid = threadIdx.x;
  const int wave = tid >> 6, lane = tid & 63;
  const int row0 = blockIdx.x * 64;
  if (tid < 128) {
    const int n = tid >> 3, k16 = tid & 7;
    const uint4 w = *(const uint4*)((const char*)pwT + n * 128 + k16 * 16);
    *(uint4*)((char*)Bs + ((n * 128 + k16 * 16) ^ ((n & 7) << 4))) = w;
  }
  #pragma unroll
  for (int i = 0; i < 2; ++i) {
    const int id = i * 256 + tid;
    const int rr = id >> 3, k16 = id & 7;
    int gr = row0 + rr; if (gr > M - 1) gr = M - 1;
    const uint4 w = *(const uint4*)(g2 + (size_t)gr * 64 + k16 * 8);
    *(uint4*)((char*)As + ((rr * 128 + k16 * 16) ^ ((rr & 7) << 4))) = w;
  }
  __syncthreads();
  const int lm = lane & 15, lk16 = (lane >> 4) * 16;
  f32x4 acc4 = (f32x4){0.f, 0.f, 0.f, 0.f};
  #pragma unroll
  for (int ks = 0; ks < 2; ++ks) {
    const int rrow = wave * 16 + lm;
    const bf16x8 a = *(bf16x8*)((char*)As + ((rrow * 128 + ks * 64 + lk16) ^ ((rrow & 7) << 4)));
    const bf16x8 b = *(bf16x8*)((char*)Bs + ((lm * 128 + ks * 64 + lk16) ^ ((lm & 7) << 4)));
    acc4 = __builtin_amdgcn_mfma_f32_16x16x32_bf16(a, b, acc4, 0, 0, 0);
  }
  if (lm < 8) {
    const float pbv = pred_b[lm];
    const int gr0 = row0 + wave * 16 + (lane >> 4) * 4;
    #pragma unroll
    for (int i = 0; i < 4; ++i) {
      const int gr = gr0 + i;
      if (gr < M) out[(size_t)gr * 8 + lm] = acc4[i] + pbv;
    }
  }
}

extern "C" void kernel_launch(void* const* d_in, const int* in_sizes, int n_in,
                              void* d_out, int out_size, void* d_ws, size_t ws_size,
                              hipStream_t stream) {
  const float* feat0  = (const float*)d_in[0];
  const float* feat1  = (const float*)d_in[1];
  const float* fc0_w  = (const float*)d_in[2];
  const float* fc0_b  = (const float*)d_in[3];
  const float* fc1_w  = (const float*)d_in[4];
  const float* fc1_b  = (const float*)d_in[5];
  const float* W1     = (const float*)d_in[6];
  const float* b1     = (const float*)d_in[7];
  const float* W2     = (const float*)d_in[8];
  const float* b2     = (const float*)d_in[9];
  const float* pred_w = (const float*)d_in[10];
  const float* pred_b = (const float*)d_in[11];
  const int*   erow   = (const int*)d_in[12];
  const int*   ecol   = (const int*)d_in[13];
  const float* ew     = (const float*)d_in[14];
  float* out = (float*)d_out;
  const int nE = in_sizes[12];
  const int N = N_NODES;

  char* ws = (char*)d_ws;
  size_t off = 0;
  unsigned short* M0T = (unsigned short*)(ws + off); off += 32768;
  unsigned short* M1T = (unsigned short*)(ws + off); off += 65536;
  unsigned short* W2T = (unsigned short*)(ws + off); off += 16384;
  unsigned short* pwT = (unsigned short*)(ws + off); off += 2048;
  float* cb   = (float*)(ws + off); off += 1024;
  int* gh     = (int*)(ws + off); off += (size_t)NBUCK2 * NB1 * 4;       // 150.5 KB
  int* gbase  = (int*)(ws + off); off += (size_t)NB1 * 256 * 4;          // 196.6 KB
  int* bcnt   = (int*)(ws + off); off += 1024;
  uint2* tmp  = (uint2*)(ws + off); off += (size_t)NBUCK2 * CAP2 * 8;    // 14.5 MB
  unsigned* spack = (unsigned*)(ws + off); off += (size_t)NBUCK2 * CAP2 * 4;  // 7.2 MB
  int2* row_se = (int2*)(ws + off); off += (size_t)N * 8;                // 800 KB
  unsigned short* h  = (unsigned short*)(ws + off); off += (size_t)N * 128 * 2;  // 25.6 MB
  unsigned short* g1 = (unsigned short*)(ws + off); off += (size_t)N * 128 * 2;  // 25.6 MB
  unsigned short* h2 = (unsigned short*)(ws + off); off += (size_t)N * 64 * 2;   // 12.8 MB
  unsigned short* g2 = (unsigned short*)(ws + off); off += (size_t)N * 64 * 2;   // 12.8 MB

  // ---- CSR build: hist -> scan -> scatter -> per-bucket sort (no global atomics) ----
  hipLaunchKernelGGL(hist1_kernel, dim3(NB1), dim3(512), 0, stream, erow, gh, nE);
  hipLaunchKernelGGL(scan_kernel, dim3(1), dim3(256), 0, stream, gh, gbase, bcnt);
  hipLaunchKernelGGL(scatter1_kernel, dim3(NB1), dim3(512), 0, stream,
                     erow, ecol, ew, gbase, tmp, nE);
  hipLaunchKernelGGL(part2_kernel, dim3(NBUCK2), dim3(512), 0, stream,
                     bcnt, tmp, spack, row_se, N);

  // ---- dense pipeline ----
  hipLaunchKernelGGL(prep_small_kernel, dim3(229), dim3(256), 0, stream,
                     fc0_w, fc1_w, fc0_b, fc1_b, W1, W2, pred_w,
                     M0T, M1T, W2T, pwT, cb);
  hipLaunchKernelGGL((mfma_gemm_kernel<128, 128>), dim3((N_TYPE + 63) / 64), dim3(256),
                     0, stream, feat0, M0T, cb, h, N_TYPE);
  hipLaunchKernelGGL((mfma_gemm_kernel<128, 256>), dim3((N_TYPE + 63) / 64), dim3(256),
                     0, stream, feat1, M1T, cb + 128, h + (size_t)N_TYPE * 128, N_TYPE);
  // g1 = bf16(relu(adj @ h + b1))
  hipLaunchKernelGGL(spmm1_kernel, dim3((N * 32 + 255) / 256), dim3(256), 0, stream,
                     h, row_se, spack, b1, g1, N);
  // h2 = bf16(g1 @ W2)
  hipLaunchKernelGGL(gemmA64_kernel, dim3((N + 63) / 64), dim3(256), 0, stream,
                     g1, W2T, h2, N);
  // g2 = bf16(relu(adj @ h2 + b2))
  hipLaunchKernelGGL(spmm2_kernel, dim3((N * 32 + 255) / 256), dim3(256), 0, stream,
                     h2, row_se, spack, b2, g2, N);
  // out = g2 @ pred_w^T + pred_b
  hipLaunchKernelGGL(head_kernel, dim3((N + 63) / 64), dim3(256), 0, stream,
                     g2, pwT, pred_b, out, N);
}